// Round 8
// baseline (1932.569 us; speedup 1.0000x reference)
//
#include <hip/hip_runtime.h>

#define NB 128
#define NT 80
#define NI 4096
#define NH 256
#define G4 1024
#define NV 6000
#define NVP 6016
#define NDEC 40

typedef unsigned short ushort_t;
typedef __attribute__((ext_vector_type(8))) short bf16x8;
typedef __attribute__((ext_vector_type(4))) float f32x4;

__device__ __forceinline__ unsigned short f2bf(float f) {
  unsigned int x = __float_as_uint(f);
  x += 0x7FFFu + ((x >> 16) & 1u);
  return (unsigned short)(x >> 16);
}
__device__ __forceinline__ ushort4 pack4(float4 v) {
  return make_ushort4(f2bf(v.x), f2bf(v.y), f2bf(v.z), f2bf(v.w));
}

// ---------------- cast kernels ----------------

__global__ __launch_bounds__(256) void k_cast_x(const float* __restrict__ x,
                                                ushort_t* __restrict__ xb) {
  const int t = blockIdx.x, b = blockIdx.y;
  const float* src = x + ((size_t)b * NT + t) * NI;
  ushort_t* dst = xb + ((size_t)t * NB + b) * NI;
#pragma unroll
  for (int s = 0; s < 4; ++s) {
    int j = s * 1024 + threadIdx.x * 4;
    float4 v = *(const float4*)(src + j);
    *(ushort4*)(dst + j) = pack4(v);
  }
}

__global__ __launch_bounds__(256) void k_cast_pad(const float* __restrict__ s,
                                                  ushort_t* __restrict__ d,
                                                  int nsrc, int ndst) {
  int i = (blockIdx.x * 256 + threadIdx.x) * 4;
  if (i >= ndst) return;
  ushort4 o;
  if (i < nsrc) {
    float4 v = *(const float4*)(s + i);
    o = pack4(v);
  } else {
    o = make_ushort4(0, 0, 0, 0);
  }
  *(ushort4*)(d + i) = o;
}

// o = bf16(a + b)
__global__ __launch_bounds__(256) void k_addw_bf(const float* __restrict__ a,
                                                 const float* __restrict__ b,
                                                 ushort_t* __restrict__ o) {
  int i = (blockIdx.x * 256 + threadIdx.x) * 4;
  float4 va = *(const float4*)(a + i);
  float4 vb = *(const float4*)(b + i);
  va.x += vb.x; va.y += vb.y; va.z += vb.z; va.w += vb.w;
  *(ushort4*)(o + i) = pack4(va);
}

// ---------------- bf16 MFMA GEMM: C = A @ B^T + bias_a + bias_b ----------------

#define GLDS(gp, lp)                                                     \
  __builtin_amdgcn_global_load_lds(                                      \
      (const __attribute__((address_space(1))) unsigned int*)(gp),       \
      (__attribute__((address_space(3))) unsigned int*)(lp), 16, 0, 0)

__global__ __launch_bounds__(256) void k_gemm(
    const ushort_t* __restrict__ A, const ushort_t* __restrict__ Bm,
    float* __restrict__ C, const float* __restrict__ ba,
    const float* __restrict__ bb, int Nreal, int K, int ldc, int mtiles) {
  __shared__ __align__(16) ushort_t Als[128 * 32];
  __shared__ __align__(16) ushort_t Bls[128 * 32];
  const int bid = blockIdx.x;
  const int mt = bid % mtiles, nt = bid / mtiles;
  const size_t m0 = (size_t)mt * 128, n0 = (size_t)nt * 128;
  const int tid = threadIdx.x, wave = tid >> 6, lane = tid & 63;
  const int wm = (wave & 1) * 64, wn = (wave >> 1) * 64;
  const int srow = wave * 16 + (lane >> 2), skcol = (lane & 3) * 8;
  const int fr = lane & 15, kb = (lane >> 4) * 8;

  f32x4 acc[4][4];
#pragma unroll
  for (int i = 0; i < 4; ++i)
#pragma unroll
    for (int j = 0; j < 4; ++j) acc[i][j] = (f32x4){0.f, 0.f, 0.f, 0.f};

  for (int kk = 0; kk < K; kk += 32) {
    __syncthreads();
#pragma unroll
    for (int p = 0; p < 2; ++p) {
      GLDS(A + (m0 + p * 64 + srow) * K + kk + skcol,
           &Als[(p * 64 + wave * 16) * 32]);
      GLDS(Bm + (n0 + p * 64 + srow) * K + kk + skcol,
           &Bls[(p * 64 + wave * 16) * 32]);
    }
    __syncthreads();
    bf16x8 af[4], bfr[4];
#pragma unroll
    for (int i = 0; i < 4; ++i)
      af[i] = *(const bf16x8*)&Als[(wm + i * 16 + fr) * 32 + kb];
#pragma unroll
    for (int j = 0; j < 4; ++j)
      bfr[j] = *(const bf16x8*)&Bls[(wn + j * 16 + fr) * 32 + kb];
#pragma unroll
    for (int i = 0; i < 4; ++i)
#pragma unroll
      for (int j = 0; j < 4; ++j)
        acc[i][j] = __builtin_amdgcn_mfma_f32_16x16x32_bf16(af[i], bfr[j],
                                                            acc[i][j], 0, 0, 0);
  }
  const int cr4 = (lane >> 4) * 4, ccn = lane & 15;
#pragma unroll
  for (int j = 0; j < 4; ++j) {
    int n = (int)n0 + wn + j * 16 + ccn;
    if (n < Nreal) {
      float bv = (ba ? ba[n] : 0.f) + (bb ? bb[n] : 0.f);
#pragma unroll
      for (int i = 0; i < 4; ++i) {
#pragma unroll
        for (int r = 0; r < 4; ++r) {
          size_t m = m0 + wm + i * 16 + cr4 + r;
          C[m * (size_t)ldc + n] = acc[i][j][r] + bv;
        }
      }
    }
  }
}

// ---------------- W-resident persistent LSTM chain (NO grid sync) ----------------
// 16 blocks x 512 threads (8 waves, 1 block/CU). Block bg owns batch rows
// [bg*8, bg*8+8). Wave wv owns hidden cols [wv*32, wv*32+32): W tiles for gates
// i,f,g (both 16-col halves) in 192 VGPRs (PINNED via opaque asm so the
// compiler cannot sink/remat the loads into the loop — round-6 failure mode),
// o-gate tiles in LDS (128 KB). h double-buffered in LDS. All four gates of a
// unit land in one lane -> in-lane activation, 1 barrier/step.

#define LOAD_WREGS(Wb)                                                        \
  _Pragma("unroll") for (int g = 0; g < 3; ++g)                               \
  _Pragma("unroll") for (int h = 0; h < 2; ++h)                               \
  _Pragma("unroll") for (int kb = 0; kb < 8; ++kb)                            \
      wr[g * 2 + h][kb] = *(const bf16x8*)((Wb) +                             \
          (size_t)(g * 256 + cbase + h * 16 + cn) * NH + kb * 32 + kgrp * 8);

// opaque pin: values become asm-defined -> must stay in VGPRs across the loop
#define PIN_W()                                                               \
  _Pragma("unroll") for (int g = 0; g < 6; ++g)                               \
  _Pragma("unroll") for (int kb = 0; kb < 8; ++kb)                            \
      asm volatile("" : "+v"(wr[g][kb]));

#define LOAD_WLDS(Wb)                                                         \
  _Pragma("unroll") for (int h = 0; h < 2; ++h)                               \
  _Pragma("unroll") for (int kb = 0; kb < 8; ++kb)                            \
      *(bf16x8*)&WL[wv * 8192 + h * 4096 + kb * 512 + cn * 32 + kgrp * 8] =   \
          *(const bf16x8*)((Wb) +                                             \
          (size_t)(768 + cbase + h * 16 + cn) * NH + kb * 32 + kgrp * 8);

__global__ __launch_bounds__(512, 2) void p_lstm16(
    const float* __restrict__ gIn0, const float* __restrict__ gIn1, int n0,
    int nTot, const ushort_t* __restrict__ W0, const ushort_t* __restrict__ Wsw,
    int swStep, const float* __restrict__ biasA, const float* __restrict__ biasB,
    ushort_t* __restrict__ traj0, ushort_t* __restrict__ traj1, int t1bmaj) {
  __shared__ __align__(16) ushort_t WL[8 * 8192];     // 128 KB o-gate W
  __shared__ __align__(16) ushort_t hTz[2][16 * 264]; // 2 x 8448 B h dbuf
  const int tid = threadIdx.x;
  const int bg = blockIdx.x;              // 0..15
  const int wv = tid >> 6, lane = tid & 63;
  const int cn = lane & 15;               // B col / A row / C col
  const int kgrp = lane >> 4;             // 0..3 (k slice)
  const int cbase = wv * 32;
  const int rsel = kgrp & 1;              // batch-row group for G loads

  bf16x8 wr[6][8];
  LOAD_WREGS(W0);
  PIN_W();
  LOAD_WLDS(W0);
  for (int i = tid; i < 2 * 16 * 264; i += 512) ((ushort_t*)hTz)[i] = 0;

  float cs[8];
#pragma unroll
  for (int i = 0; i < 8; ++i) cs[i] = 0.f;
  __syncthreads();

  int cur = 0;
  for (int t = 0; t < nTot; ++t) {
    if (Wsw && t == swStep) {
      LOAD_WREGS(Wsw);
      PIN_W();
      LOAD_WLDS(Wsw);
      __syncthreads();
    }
    const ushort_t* hTc = &hTz[cur][0];
    ushort_t* hTn = &hTz[cur ^ 1][0];
    const float* gseg = (t < n0) ? gIn0 : gIn1;
    const int tt = (t < n0) ? t : t - n0;
#pragma unroll
    for (int h = 0; h < 2; ++h) {
      const int gcol = cbase + h * 16 + cn;
      // input term (bias already folded into G by k_gemm)
      float in_[4][4];
      if (gseg) {
        const float* base = gseg + (size_t)tt * (NB * G4);
#pragma unroll
        for (int g = 0; g < 4; ++g)
#pragma unroll
          for (int e = 0; e < 4; ++e)
            in_[g][e] = base[(size_t)(bg * 8 + rsel * 4 + e) * G4 + g * 256 + gcol];
      } else {
#pragma unroll
        for (int g = 0; g < 4; ++g) {
          float b = biasA[g * 256 + gcol] + biasB[g * 256 + gcol];
#pragma unroll
          for (int e = 0; e < 4; ++e) in_[g][e] = b;
        }
      }
      f32x4 acc[4];
#pragma unroll
      for (int g = 0; g < 4; ++g) acc[g] = (f32x4){0.f, 0.f, 0.f, 0.f};
#pragma unroll
      for (int kb = 0; kb < 8; ++kb) {
        bf16x8 af = *(const bf16x8*)&hTc[cn * 264 + kb * 32 + kgrp * 8];
        bf16x8 bo = *(const bf16x8*)&WL[wv * 8192 + h * 4096 + kb * 512 +
                                        cn * 32 + kgrp * 8];
        acc[0] = __builtin_amdgcn_mfma_f32_16x16x32_bf16(af, wr[0 + h][kb],
                                                         acc[0], 0, 0, 0);
        acc[1] = __builtin_amdgcn_mfma_f32_16x16x32_bf16(af, wr[2 + h][kb],
                                                         acc[1], 0, 0, 0);
        acc[2] = __builtin_amdgcn_mfma_f32_16x16x32_bf16(af, wr[4 + h][kb],
                                                         acc[2], 0, 0, 0);
        acc[3] = __builtin_amdgcn_mfma_f32_16x16x32_bf16(af, bo, acc[3], 0, 0, 0);
      }
      // in-lane activation: lane holds (batch=(lane>>4)*4+e, col=gcol)
#pragma unroll
      for (int e = 0; e < 4; ++e) {
        float a0 = acc[0][e] + in_[0][e];
        float a1 = acc[1][e] + in_[1][e];
        float a2 = acc[2][e] + in_[2][e];
        float a3 = acc[3][e] + in_[3][e];
        float ig = 1.f / (1.f + __expf(-a0));
        float fg = 1.f / (1.f + __expf(-a1));
        float gg = tanhf(a2);
        float og = 1.f / (1.f + __expf(-a3));
        float cn_ = fg * cs[h * 4 + e] + ig * gg;
        cs[h * 4 + e] = cn_;
        float hn = og * tanhf(cn_);
        unsigned short hb = f2bf(hn);
        if (lane < 32) {
          const int b = (lane >> 4) * 4 + e;  // 0..7
          hTn[b * 264 + gcol] = hb;
          const int bglob = bg * 8 + b;
          if (t < n0) {
            if (traj0)
              traj0[(size_t)t * (NB * NH) + (size_t)bglob * NH + gcol] = hb;
          } else if (traj1) {
            size_t idx =
                t1bmaj ? ((size_t)bglob * NDEC + (t - n0)) * NH + gcol
                       : (size_t)(t - n0) * (NB * NH) + (size_t)bglob * NH + gcol;
            traj1[idx] = hb;
          }
        }
      }
    }
    __syncthreads();
    cur ^= 1;
  }
}

// ---------------- host ----------------

extern "C" void kernel_launch(void* const* d_in, const int* in_sizes, int n_in,
                              void* d_out, int out_size, void* d_ws,
                              size_t ws_size, hipStream_t stream) {
  const float* x = (const float*)d_in[0];
  const float* Wih1 = (const float*)d_in[1];
  const float* Whh1 = (const float*)d_in[2];
  const float* bih1 = (const float*)d_in[3];
  const float* bhh1 = (const float*)d_in[4];
  const float* Wih2 = (const float*)d_in[5];
  const float* Whh2 = (const float*)d_in[6];
  const float* bih2 = (const float*)d_in[7];
  const float* bhh2 = (const float*)d_in[8];
  const float* Wout = (const float*)d_in[9];
  const float* bout = (const float*)d_in[10];
  char* ws = (char*)d_ws;

  // ws layout (bytes)
  ushort_t* x_bf   = (ushort_t*)(ws + 0);           //  83,886,080 (T,B,I) bf16
  float*    Gbuf3  = (float*)(ws + 0);              //  20,971,520 (reuses x_bf)
  float*    Gbuf   = (float*)(ws + 83886080);       //  41,943,040
  ushort_t* Wih1b  = (ushort_t*)(ws + 125829120);   //   8,388,608
  ushort_t* Wih2b  = (ushort_t*)(ws + 134217728);   //     524,288
  ushort_t* Woutb  = (ushort_t*)(ws + 134742016);   //   3,080,192 (6016x256)
  ushort_t* Whh1b  = (ushort_t*)(ws + 137822208);   //     524,288
  ushort_t* Whh2b  = (ushort_t*)(ws + 138346496);   //     524,288
  ushort_t* ys1    = (ushort_t*)(ws + 138870784);   //   5,242,880 (80,128,256)
  ushort_t* H1dec  = (ushort_t*)(ws + 144113664);   //   2,686,976 (41,128,256)
  ushort_t* feats  = (ushort_t*)(ws + 146800640);   //   2,621,440 (128,40,256)
  ushort_t* Wsumb  = (ushort_t*)(ws + 149422080);   //     524,288 bf16(Wih2+Whh2)

  // casts + weight prep
  k_cast_x<<<dim3(NT, NB), 256, 0, stream>>>(x, x_bf);
  k_cast_pad<<<4096, 256, 0, stream>>>(Wih1, Wih1b, G4 * NI, G4 * NI);
  k_cast_pad<<<256, 256, 0, stream>>>(Wih2, Wih2b, G4 * NH, G4 * NH);
  k_cast_pad<<<1504, 256, 0, stream>>>(Wout, Woutb, NV * NH, NVP * NH);
  k_cast_pad<<<256, 256, 0, stream>>>(Whh1, Whh1b, G4 * NH, G4 * NH);
  k_cast_pad<<<256, 256, 0, stream>>>(Whh2, Whh2b, G4 * NH, G4 * NH);
  k_addw_bf<<<256, 256, 0, stream>>>(Wih2, Whh2, Wsumb);

  // G1 = x_bf @ Wih1^T + b1 : (10240, 1024), K=4096
  k_gemm<<<640, 256, 0, stream>>>(x_bf, Wih1b, Gbuf, bih1, bhh1, G4, NI, G4, 80);

  // persistent lstm1: 80 encode steps (input G1) + 41 pad steps (bias input)
  p_lstm16<<<16, 512, 0, stream>>>(Gbuf, nullptr, NT, NT + NDEC + 1, Whh1b,
                                   nullptr, 1 << 30, bih1, bhh1, ys1, H1dec, 0);

  // G2 = ys1 @ Wih2^T + b2 ; G3 = H1dec[1..40] @ Wih2^T + b2 (into x_bf region)
  k_gemm<<<640, 256, 0, stream>>>(ys1, Wih2b, Gbuf, bih2, bhh2, G4, NH, G4, 80);
  k_gemm<<<320, 256, 0, stream>>>(H1dec + (size_t)NB * NH, Wih2b, Gbuf3, bih2,
                                  bhh2, G4, NH, G4, 40);

  // persistent lstm2: 80 encode (G2, W=Whh2b) + 40 decode (G3; Wsumb from t=81
  // since y2==h2 for k>=1)
  p_lstm16<<<16, 512, 0, stream>>>(Gbuf, Gbuf3, NT, NT + NDEC, Whh2b, Wsumb,
                                   NT + 1, nullptr, nullptr, nullptr, feats, 1);

  // logits = feats @ Wout^T + b_out : (5120, 6000)
  k_gemm<<<40 * 47, 256, 0, stream>>>(feats, Woutb, (float*)d_out, bout, nullptr,
                                      NV, NH, NV, 40);
}

// Round 11
// 1855.432 us; speedup vs baseline: 1.0416x; 1.0416x over previous
//
#include <hip/hip_runtime.h>

#define NB 128
#define NT 80
#define NI 4096
#define NH 256
#define G4 1024
#define NV 6000
#define NVP 6016
#define NDEC 40

typedef unsigned short ushort_t;
typedef __attribute__((ext_vector_type(8))) short bf16x8;
typedef __attribute__((ext_vector_type(4))) float f32x4;

__device__ __forceinline__ unsigned short f2bf(float f) {
  unsigned int x = __float_as_uint(f);
  x += 0x7FFFu + ((x >> 16) & 1u);
  return (unsigned short)(x >> 16);
}
__device__ __forceinline__ ushort4 pack4(float4 v) {
  return make_ushort4(f2bf(v.x), f2bf(v.y), f2bf(v.z), f2bf(v.w));
}

// ---------------- cast kernels ----------------

__global__ __launch_bounds__(256) void k_cast_x(const float* __restrict__ x,
                                                ushort_t* __restrict__ xb) {
  const int t = blockIdx.x, b = blockIdx.y;
  const float* src = x + ((size_t)b * NT + t) * NI;
  ushort_t* dst = xb + ((size_t)t * NB + b) * NI;
#pragma unroll
  for (int s = 0; s < 4; ++s) {
    int j = s * 1024 + threadIdx.x * 4;
    float4 v = *(const float4*)(src + j);
    *(ushort4*)(dst + j) = pack4(v);
  }
}

__global__ __launch_bounds__(256) void k_cast_pad(const float* __restrict__ s,
                                                  ushort_t* __restrict__ d,
                                                  int nsrc, int ndst) {
  int i = (blockIdx.x * 256 + threadIdx.x) * 4;
  if (i >= ndst) return;
  ushort4 o;
  if (i < nsrc) {
    float4 v = *(const float4*)(s + i);
    o = pack4(v);
  } else {
    o = make_ushort4(0, 0, 0, 0);
  }
  *(ushort4*)(d + i) = o;
}

// o = bf16(a + b)
__global__ __launch_bounds__(256) void k_addw_bf(const float* __restrict__ a,
                                                 const float* __restrict__ b,
                                                 ushort_t* __restrict__ o) {
  int i = (blockIdx.x * 256 + threadIdx.x) * 4;
  float4 va = *(const float4*)(a + i);
  float4 vb = *(const float4*)(b + i);
  va.x += vb.x; va.y += vb.y; va.z += vb.z; va.w += vb.w;
  *(ushort4*)(o + i) = pack4(va);
}

// ---------------- bf16 MFMA GEMM: C = A @ B^T + bias_a + bias_b ----------------

#define GLDS(gp, lp)                                                     \
  __builtin_amdgcn_global_load_lds(                                      \
      (const __attribute__((address_space(1))) unsigned int*)(gp),       \
      (__attribute__((address_space(3))) unsigned int*)(lp), 16, 0, 0)

__global__ __launch_bounds__(256) void k_gemm(
    const ushort_t* __restrict__ A, const ushort_t* __restrict__ Bm,
    float* __restrict__ C, const float* __restrict__ ba,
    const float* __restrict__ bb, int Nreal, int K, int ldc, int mtiles) {
  __shared__ __align__(16) ushort_t Als[128 * 32];
  __shared__ __align__(16) ushort_t Bls[128 * 32];
  const int bid = blockIdx.x;
  const int mt = bid % mtiles, nt = bid / mtiles;
  const size_t m0 = (size_t)mt * 128, n0 = (size_t)nt * 128;
  const int tid = threadIdx.x, wave = tid >> 6, lane = tid & 63;
  const int wm = (wave & 1) * 64, wn = (wave >> 1) * 64;
  const int srow = wave * 16 + (lane >> 2), skcol = (lane & 3) * 8;
  const int fr = lane & 15, kb = (lane >> 4) * 8;

  f32x4 acc[4][4];
#pragma unroll
  for (int i = 0; i < 4; ++i)
#pragma unroll
    for (int j = 0; j < 4; ++j) acc[i][j] = (f32x4){0.f, 0.f, 0.f, 0.f};

  for (int kk = 0; kk < K; kk += 32) {
    __syncthreads();
#pragma unroll
    for (int p = 0; p < 2; ++p) {
      GLDS(A + (m0 + p * 64 + srow) * K + kk + skcol,
           &Als[(p * 64 + wave * 16) * 32]);
      GLDS(Bm + (n0 + p * 64 + srow) * K + kk + skcol,
           &Bls[(p * 64 + wave * 16) * 32]);
    }
    __syncthreads();
    bf16x8 af[4], bfr[4];
#pragma unroll
    for (int i = 0; i < 4; ++i)
      af[i] = *(const bf16x8*)&Als[(wm + i * 16 + fr) * 32 + kb];
#pragma unroll
    for (int j = 0; j < 4; ++j)
      bfr[j] = *(const bf16x8*)&Bls[(wn + j * 16 + fr) * 32 + kb];
#pragma unroll
    for (int i = 0; i < 4; ++i)
#pragma unroll
      for (int j = 0; j < 4; ++j)
        acc[i][j] = __builtin_amdgcn_mfma_f32_16x16x32_bf16(af[i], bfr[j],
                                                            acc[i][j], 0, 0, 0);
  }
  const int cr4 = (lane >> 4) * 4, ccn = lane & 15;
#pragma unroll
  for (int j = 0; j < 4; ++j) {
    int n = (int)n0 + wn + j * 16 + ccn;
    if (n < Nreal) {
      float bv = (ba ? ba[n] : 0.f) + (bb ? bb[n] : 0.f);
#pragma unroll
      for (int i = 0; i < 4; ++i) {
#pragma unroll
        for (int r = 0; r < 4; ++r) {
          size_t m = m0 + wm + i * 16 + cr4 + r;
          C[m * (size_t)ldc + n] = acc[i][j][r] + bv;
        }
      }
    }
  }
}

// ---------------- W-resident persistent LSTM chain (NO grid sync) ----------------
// 16 blocks x 512 threads (8 waves, 1 block/CU — LDS-bound). Block bg owns
// batch rows [bg*8, bg*8+8). Wave wv owns hidden cols [wv*32, wv*32+32):
// W tiles for gates i,f,g (both 16-col halves) pinned in 192 AGPRs per lane
// ("+a" asm pin; gfx950 MFMA reads A/B from AGPRs natively, and the AGPR file
// has zero other pressure — round-6/8 failure was the 128-VGPR cap forcing
// re-streaming). o-gate tiles in LDS (128 KB). h double-buffered in LDS.
// All four gates of a unit land in one lane -> in-lane activation, 1 barrier/step.

#define LOAD_WREGS(Wb)                                                        \
  _Pragma("unroll") for (int g = 0; g < 3; ++g)                               \
  _Pragma("unroll") for (int h = 0; h < 2; ++h)                               \
  _Pragma("unroll") for (int kb = 0; kb < 8; ++kb)                            \
      wr[g * 2 + h][kb] = *(const bf16x8*)((Wb) +                             \
          (size_t)(g * 256 + cbase + h * 16 + cn) * NH + kb * 32 + kgrp * 8);

// AGPR pin: values live in the accumulator file across the whole loop
#define PIN_W()                                                               \
  _Pragma("unroll") for (int g = 0; g < 6; ++g)                               \
  _Pragma("unroll") for (int kb = 0; kb < 8; ++kb)                            \
      asm volatile("" : "+a"(wr[g][kb]));

#define LOAD_WLDS(Wb)                                                         \
  _Pragma("unroll") for (int h = 0; h < 2; ++h)                               \
  _Pragma("unroll") for (int kb = 0; kb < 8; ++kb)                            \
      *(bf16x8*)&WL[wv * 8192 + h * 4096 + kb * 512 + cn * 32 + kgrp * 8] =   \
          *(const bf16x8*)((Wb) +                                             \
          (size_t)(768 + cbase + h * 16 + cn) * NH + kb * 32 + kgrp * 8);

__global__ __launch_bounds__(512) void p_lstm16(
    const float* __restrict__ gIn0, const float* __restrict__ gIn1, int n0,
    int nTot, const ushort_t* __restrict__ W0, const ushort_t* __restrict__ Wsw,
    int swStep, const float* __restrict__ biasA, const float* __restrict__ biasB,
    ushort_t* __restrict__ traj0, ushort_t* __restrict__ traj1, int t1bmaj) {
  __shared__ __align__(16) ushort_t WL[8 * 8192];     // 128 KB o-gate W
  __shared__ __align__(16) ushort_t hTz[2][16 * 264]; // 2 x 8448 B h dbuf
  const int tid = threadIdx.x;
  const int bg = blockIdx.x;              // 0..15
  const int wv = tid >> 6, lane = tid & 63;
  const int cn = lane & 15;               // B col / A row / C col
  const int kgrp = lane >> 4;             // 0..3 (k slice)
  const int cbase = wv * 32;
  const int rsel = kgrp & 1;              // batch-row group for G loads

  bf16x8 wr[6][8];
  LOAD_WREGS(W0);
  PIN_W();
  LOAD_WLDS(W0);
  for (int i = tid; i < 2 * 16 * 264; i += 512) ((ushort_t*)hTz)[i] = 0;

  float cs[8];
#pragma unroll
  for (int i = 0; i < 8; ++i) cs[i] = 0.f;
  __syncthreads();

  int cur = 0;
  for (int t = 0; t < nTot; ++t) {
    if (Wsw && t == swStep) {
      LOAD_WREGS(Wsw);
      PIN_W();
      LOAD_WLDS(Wsw);
      __syncthreads();
    }
    const ushort_t* hTc = &hTz[cur][0];
    ushort_t* hTn = &hTz[cur ^ 1][0];
    const float* gseg = (t < n0) ? gIn0 : gIn1;
    const int tt = (t < n0) ? t : t - n0;
#pragma unroll
    for (int h = 0; h < 2; ++h) {
      const int gcol = cbase + h * 16 + cn;
      // input term (bias already folded into G by k_gemm)
      float in_[4][4];
      if (gseg) {
        const float* base = gseg + (size_t)tt * (NB * G4);
#pragma unroll
        for (int g = 0; g < 4; ++g)
#pragma unroll
          for (int e = 0; e < 4; ++e)
            in_[g][e] = base[(size_t)(bg * 8 + rsel * 4 + e) * G4 + g * 256 + gcol];
      } else {
#pragma unroll
        for (int g = 0; g < 4; ++g) {
          float b = biasA[g * 256 + gcol] + biasB[g * 256 + gcol];
#pragma unroll
          for (int e = 0; e < 4; ++e) in_[g][e] = b;
        }
      }
      f32x4 acc[4];
#pragma unroll
      for (int g = 0; g < 4; ++g) acc[g] = (f32x4){0.f, 0.f, 0.f, 0.f};
#pragma unroll
      for (int kb = 0; kb < 8; ++kb) {
        bf16x8 af = *(const bf16x8*)&hTc[cn * 264 + kb * 32 + kgrp * 8];
        bf16x8 bo = *(const bf16x8*)&WL[wv * 8192 + h * 4096 + kb * 512 +
                                        cn * 32 + kgrp * 8];
        acc[0] = __builtin_amdgcn_mfma_f32_16x16x32_bf16(af, wr[0 + h][kb],
                                                         acc[0], 0, 0, 0);
        acc[1] = __builtin_amdgcn_mfma_f32_16x16x32_bf16(af, wr[2 + h][kb],
                                                         acc[1], 0, 0, 0);
        acc[2] = __builtin_amdgcn_mfma_f32_16x16x32_bf16(af, wr[4 + h][kb],
                                                         acc[2], 0, 0, 0);
        acc[3] = __builtin_amdgcn_mfma_f32_16x16x32_bf16(af, bo, acc[3], 0, 0, 0);
      }
      // in-lane activation: lane holds (batch=(lane>>4)*4+e, col=gcol)
#pragma unroll
      for (int e = 0; e < 4; ++e) {
        float a0 = acc[0][e] + in_[0][e];
        float a1 = acc[1][e] + in_[1][e];
        float a2 = acc[2][e] + in_[2][e];
        float a3 = acc[3][e] + in_[3][e];
        float ig = 1.f / (1.f + __expf(-a0));
        float fg = 1.f / (1.f + __expf(-a1));
        float gg = tanhf(a2);
        float og = 1.f / (1.f + __expf(-a3));
        float cn_ = fg * cs[h * 4 + e] + ig * gg;
        cs[h * 4 + e] = cn_;
        float hn = og * tanhf(cn_);
        unsigned short hb = f2bf(hn);
        if (lane < 32) {
          const int b = (lane >> 4) * 4 + e;  // 0..7
          hTn[b * 264 + gcol] = hb;
          const int bglob = bg * 8 + b;
          if (t < n0) {
            if (traj0)
              traj0[(size_t)t * (NB * NH) + (size_t)bglob * NH + gcol] = hb;
          } else if (traj1) {
            size_t idx =
                t1bmaj ? ((size_t)bglob * NDEC + (t - n0)) * NH + gcol
                       : (size_t)(t - n0) * (NB * NH) + (size_t)bglob * NH + gcol;
            traj1[idx] = hb;
          }
        }
      }
    }
    __syncthreads();
    cur ^= 1;
  }
}

// ---------------- host ----------------

extern "C" void kernel_launch(void* const* d_in, const int* in_sizes, int n_in,
                              void* d_out, int out_size, void* d_ws,
                              size_t ws_size, hipStream_t stream) {
  const float* x = (const float*)d_in[0];
  const float* Wih1 = (const float*)d_in[1];
  const float* Whh1 = (const float*)d_in[2];
  const float* bih1 = (const float*)d_in[3];
  const float* bhh1 = (const float*)d_in[4];
  const float* Wih2 = (const float*)d_in[5];
  const float* Whh2 = (const float*)d_in[6];
  const float* bih2 = (const float*)d_in[7];
  const float* bhh2 = (const float*)d_in[8];
  const float* Wout = (const float*)d_in[9];
  const float* bout = (const float*)d_in[10];
  char* ws = (char*)d_ws;

  // ws layout (bytes)
  ushort_t* x_bf   = (ushort_t*)(ws + 0);           //  83,886,080 (T,B,I) bf16
  float*    Gbuf3  = (float*)(ws + 0);              //  20,971,520 (reuses x_bf)
  float*    Gbuf   = (float*)(ws + 83886080);       //  41,943,040
  ushort_t* Wih1b  = (ushort_t*)(ws + 125829120);   //   8,388,608
  ushort_t* Wih2b  = (ushort_t*)(ws + 134217728);   //     524,288
  ushort_t* Woutb  = (ushort_t*)(ws + 134742016);   //   3,080,192 (6016x256)
  ushort_t* Whh1b  = (ushort_t*)(ws + 137822208);   //     524,288
  ushort_t* Whh2b  = (ushort_t*)(ws + 138346496);   //     524,288
  ushort_t* ys1    = (ushort_t*)(ws + 138870784);   //   5,242,880 (80,128,256)
  ushort_t* H1dec  = (ushort_t*)(ws + 144113664);   //   2,686,976 (41,128,256)
  ushort_t* feats  = (ushort_t*)(ws + 146800640);   //   2,621,440 (128,40,256)
  ushort_t* Wsumb  = (ushort_t*)(ws + 149422080);   //     524,288 bf16(Wih2+Whh2)

  // casts + weight prep
  k_cast_x<<<dim3(NT, NB), 256, 0, stream>>>(x, x_bf);
  k_cast_pad<<<4096, 256, 0, stream>>>(Wih1, Wih1b, G4 * NI, G4 * NI);
  k_cast_pad<<<256, 256, 0, stream>>>(Wih2, Wih2b, G4 * NH, G4 * NH);
  k_cast_pad<<<1504, 256, 0, stream>>>(Wout, Woutb, NV * NH, NVP * NH);
  k_cast_pad<<<256, 256, 0, stream>>>(Whh1, Whh1b, G4 * NH, G4 * NH);
  k_cast_pad<<<256, 256, 0, stream>>>(Whh2, Whh2b, G4 * NH, G4 * NH);
  k_addw_bf<<<256, 256, 0, stream>>>(Wih2, Whh2, Wsumb);

  // G1 = x_bf @ Wih1^T + b1 : (10240, 1024), K=4096
  k_gemm<<<640, 256, 0, stream>>>(x_bf, Wih1b, Gbuf, bih1, bhh1, G4, NI, G4, 80);

  // persistent lstm1: 80 encode steps (input G1) + 41 pad steps (bias input)
  p_lstm16<<<16, 512, 0, stream>>>(Gbuf, nullptr, NT, NT + NDEC + 1, Whh1b,
                                   nullptr, 1 << 30, bih1, bhh1, ys1, H1dec, 0);

  // G2 = ys1 @ Wih2^T + b2 ; G3 = H1dec[1..40] @ Wih2^T + b2 (into x_bf region)
  k_gemm<<<640, 256, 0, stream>>>(ys1, Wih2b, Gbuf, bih2, bhh2, G4, NH, G4, 80);
  k_gemm<<<320, 256, 0, stream>>>(H1dec + (size_t)NB * NH, Wih2b, Gbuf3, bih2,
                                  bhh2, G4, NH, G4, 40);

  // persistent lstm2: 80 encode (G2, W=Whh2b) + 40 decode (G3; Wsumb from t=81
  // since y2==h2 for k>=1)
  p_lstm16<<<16, 512, 0, stream>>>(Gbuf, Gbuf3, NT, NT + NDEC, Whh2b, Wsumb,
                                   NT + 1, nullptr, nullptr, nullptr, feats, 1);

  // logits = feats @ Wout^T + b_out : (5120, 6000)
  k_gemm<<<40 * 47, 256, 0, stream>>>(feats, Woutb, (float*)d_out, bout, nullptr,
                                      NV, NH, NV, 40);
}